// Round 20
// baseline (260.802 us; speedup 1.0000x reference)
//
#include <hip/hip_runtime.h>
#include <math.h>

#define TPB 256
#define TPBF 384               // fused edge kernel block (6 waves, LDS unchanged)
#define SRCS_PER_GRP 8
#define SRC_STRIDE_U16 1928    // 3856B/src, 16B-aligned per src, bank-spread

#define RMAX_F 2.5f
#define PI_F 3.14159265358979323846f
#define SQRT3_F 1.7320508075688772f
#define INV3_F 0.5773502691896258f
#define INV6_F 0.4082482904638631f
#define PW0_F 0.2041241452319315f
#define PW1_F 0.3061862178478972f
#define PWSIM_F 0.05590169943749474f
#define SILU_C_F 1.676866f
#define RB_F 0.8944271909999159f
#define INV_SQRT8_F 0.35355339059327373f

typedef unsigned short u16t;
typedef _Float16 f16x2 __attribute__((ext_vector_type(2)));

#if defined(__has_builtin)
#if __has_builtin(__builtin_amdgcn_fdot2)
#define HAVE_FDOT2 1
#else
#define HAVE_FDOT2 0
#endif
#else
#define HAVE_FDOT2 0
#endif

// ---------- helpers ----------

__device__ __forceinline__ f16x2 as_f16x2(int v) {
  union { int i; f16x2 h; } u; u.i = v; return u.h;
}
__device__ __forceinline__ unsigned f16x2_bits(f16x2 h) {
  union { f16x2 h; unsigned u; } c; c.h = h; return c.u;
}
__device__ __forceinline__ float f16b2f(u16t b) {
  union { u16t u; _Float16 h; } c; c.u = b; return (float)c.h;
}

__device__ __forceinline__ float dot2f16(f16x2 a, f16x2 b, float c) {
#if HAVE_FDOT2
  return __builtin_amdgcn_fdot2(a, b, c, false);
#else
  return fmaf((float)a.x, (float)b.x, fmaf((float)a.y, (float)b.y, c));
#endif
}

// dot of 16 f16 entries (contiguous, 16B-aligned; LDS) with packed f16 h
__device__ __forceinline__ float dotjh(const u16t* __restrict__ t,
                                       const f16x2* __restrict__ hp) {
  const int4* q = reinterpret_cast<const int4*>(t);
  int4 a = q[0], b = q[1];
  float s0 = 0.f, s1 = 0.f;
  s0 = dot2f16(as_f16x2(a.x), hp[0], s0);
  s1 = dot2f16(as_f16x2(a.y), hp[1], s1);
  s0 = dot2f16(as_f16x2(a.z), hp[2], s0);
  s1 = dot2f16(as_f16x2(a.w), hp[3], s1);
  s0 = dot2f16(as_f16x2(b.x), hp[4], s0);
  s1 = dot2f16(as_f16x2(b.y), hp[5], s1);
  s0 = dot2f16(as_f16x2(b.z), hp[6], s0);
  s1 = dot2f16(as_f16x2(b.w), hp[7], s1);
  return s0 + s1;
}

__device__ __forceinline__ void pack_h16(const float* __restrict__ h,
                                         f16x2* __restrict__ hp) {
#pragma unroll
  for (int i = 0; i < 8; ++i) {
    f16x2 v;
    v.x = (_Float16)h[2 * i + 0];
    v.y = (_Float16)h[2 * i + 1];
    hp[i] = v;
  }
}

// fallback-path helper (fp32)
__device__ __forceinline__ float dot16u(const float* __restrict__ w, const float* __restrict__ h) {
  float a0 = 0.f, a1 = 0.f, a2 = 0.f, a3 = 0.f;
#pragma unroll
  for (int j = 0; j < 16; j += 4) {
    a0 = fmaf(h[j + 0], w[j + 0], a0);
    a1 = fmaf(h[j + 1], w[j + 1], a1);
    a2 = fmaf(h[j + 2], w[j + 2], a2);
    a3 = fmaf(h[j + 3], w[j + 3], a3);
  }
  return (a0 + a1) + (a2 + a3);
}

// both nets, shared sin chain
__device__ __forceinline__ void compute_h2s(const float* __restrict__ pos,
                                            const float* __restrict__ W1k,
                                            const float* __restrict__ W1v,
                                            int src, int dst,
                                            float& shx, float& shy, float& shz,
                                            float hk[16], float hv[16]) {
  float vx = pos[3 * src + 0] - pos[3 * dst + 0];
  float vy = pos[3 * src + 1] - pos[3 * dst + 1];
  float vz = pos[3 * src + 2] - pos[3 * dst + 2];
  float r2 = fmaf(vx, vx, fmaf(vy, vy, vz * vz)) + 1e-12f;
  float r = sqrtf(r2);
  float inv_r = 1.0f / r;
  shx = SQRT3_F * vx * inv_r;
  shy = SQRT3_F * vy * inv_r;
  shz = SQRT3_F * vz * inv_r;
  float f = (r < RMAX_F) ? (RB_F * inv_r) : 0.0f;
  float t0 = (PI_F / RMAX_F) * r;
  float s1, c1;
  __sincosf(t0, &s1, &c1);
  float c2 = 2.0f * c1;
  float sm = 0.0f, sc = s1;
  float ak[16], av[16];
#pragma unroll
  for (int j = 0; j < 16; ++j) { ak[j] = 0.0f; av[j] = 0.0f; }
#pragma unroll 2
  for (int n = 0; n < 32; ++n) {
    float rb = f * sc;
    const float* wk = W1k + n * 16;
    const float* wv = W1v + n * 16;
#pragma unroll
    for (int j = 0; j < 16; ++j) ak[j] = fmaf(rb, wk[j], ak[j]);
#pragma unroll
    for (int j = 0; j < 16; ++j) av[j] = fmaf(rb, wv[j], av[j]);
    float nx = fmaf(c2, sc, -sm);
    sm = sc; sc = nx;
  }
#pragma unroll
  for (int j = 0; j < 16; ++j) {
    float v = ak[j];
    hk[j] = SILU_C_F * v * (1.0f / (1.0f + __expf(-v)));
    float w = av[j];
    hv[j] = SILU_C_F * w * (1.0f / (1.0f + __expf(-w)));
  }
}

// f16-packed table entry: acc over u of xh[u] (splat) * W2H row (8 f16x2)
__device__ __forceinline__ void gen_entry_h(const u16t* __restrict__ W2H,
                                            const unsigned* __restrict__ xh,
                                            int mm, unsigned outw[8]) {
  f16x2 acc[8];
#pragma unroll
  for (int i = 0; i < 8; ++i) { acc[i].x = (_Float16)0.f; acc[i].y = (_Float16)0.f; }
  if (mm < 16) {
    int w = mm;
#pragma unroll 1
    for (int u = 0; u < 16; ++u) {
      f16x2 xv = as_f16x2((int)xh[u]);
      const f16x2* wp = reinterpret_cast<const f16x2*>(W2H + (u * 16 + w) * 16);
#pragma unroll
      for (int i = 0; i < 8; ++i) acc[i] += xv * wp[i];
    }
  } else if (mm < 24) {
    int w = mm - 16;
#pragma unroll 1
    for (int u = 0; u < 16; ++u) {
      f16x2 xv = as_f16x2((int)xh[u]);
      const f16x2* wp = reinterpret_cast<const f16x2*>(W2H + (256 + u * 8 + w) * 16);
#pragma unroll
      for (int i = 0; i < 8; ++i) acc[i] += xv * wp[i];
    }
  } else if (mm < 48) {
    int tt = mm - 24, w = tt / 3, i3 = tt - w * 3;
#pragma unroll 1
    for (int u = 0; u < 8; ++u) {
      f16x2 xv = as_f16x2((int)xh[16 + u * 3 + i3]);
      const f16x2* wp = reinterpret_cast<const f16x2*>(W2H + (384 + u * 8 + w) * 16);
#pragma unroll
      for (int i = 0; i < 8; ++i) acc[i] += xv * wp[i];
    }
  } else if (mm < 96) {
    int tt = mm - 48, w = tt / 3, i3 = tt - w * 3;
#pragma unroll 1
    for (int u = 0; u < 8; ++u) {
      f16x2 xv = as_f16x2((int)xh[16 + u * 3 + i3]);
      const f16x2* wp = reinterpret_cast<const f16x2*>(W2H + (448 + u * 16 + w) * 16);
#pragma unroll
      for (int i = 0; i < 8; ++i) acc[i] += xv * wp[i];
    }
  } else {
    int tt = mm - 96, w = tt / 3, i3 = tt - w * 3;
#pragma unroll 1
    for (int u = 0; u < 8; ++u) {
      f16x2 xv = as_f16x2((int)xh[16 + u * 3 + i3]);
      const f16x2* wp = reinterpret_cast<const f16x2*>(W2H + (576 + u * 8 + w) * 16);
#pragma unroll
      for (int i = 0; i < 8; ++i) acc[i] += xv * wp[i];
    }
  }
#pragma unroll
  for (int i = 0; i < 8; ++i) outw[i] = f16x2_bits(acc[i]);
}

// generate one net's f16 tables for nsrc srcs into LDS (packed-f16 math)
__device__ __forceinline__ void gen_tables(const u16t* __restrict__ W2H,
                                           const unsigned* __restrict__ xh,
                                           u16t* __restrict__ tl,
                                           int nsrc, int tid) {
  for (int idx = tid; idx < nsrc * 120; idx += TPBF) {
    int m, s;
    if (nsrc == SRCS_PER_GRP) {
      m = idx >> 3;
      s = idx & 7;
    } else {
      m = idx / nsrc;
      s = idx - m * nsrc;
    }
    unsigned r[8];
    gen_entry_h(W2H, xh + s * 40, m, r);
    int4* dp = reinterpret_cast<int4*>(&tl[s * SRC_STRIDE_U16 + m * 16]);
    dp[0] = make_int4((int)r[0], (int)r[1], (int)r[2], (int)r[3]);
    dp[1] = make_int4((int)r[4], (int)r[5], (int)r[6], (int)r[7]);
  }
}

// ---------- prep device body ----------

__device__ __forceinline__ void prep_body(int i,
    const float* __restrict__ wk2, const float* __restrict__ wv2,
    const float* __restrict__ wq0, const float* __restrict__ wq1,
    const float* __restrict__ ws0, const float* __restrict__ ws1,
    float* __restrict__ W2Tk, float* __restrict__ W2Tv,
    u16t* __restrict__ W2Hk, u16t* __restrict__ W2Hv,
    float* __restrict__ C0, float* __restrict__ C1) {
  if (i < 10240) {
    int o = i >> 4, j = i & 15;
    float v = wk2[j * 640 + o] * 0.25f;
    W2Tk[i] = v;
    union { _Float16 h; u16t u; } c; c.h = (_Float16)v;
    W2Hk[i] = c.u;
  } else if (i < 20480) {
    int k = i - 10240;
    int o = k >> 4, j = k & 15;
    float v = wv2[j * 640 + o] * 0.25f;
    W2Tv[k] = v;
    union { _Float16 h; u16t u; } c; c.h = (_Float16)v;
    W2Hv[k] = c.u;
  } else if (i < 20736) {
    int k = i - 20480;
    int t = k >> 4, v = k & 15;
    float a = 0.f;
#pragma unroll
    for (int u = 0; u < 16; ++u) a = fmaf(wq0[t * 16 + u] * 0.25f, ws0[u * 16 + v], a);
    C0[k] = a;
  } else if (i < 20800) {
    int k = i - 20736;
    int t = k >> 3, v = k & 7;
    float a = 0.f;
#pragma unroll
    for (int u = 0; u < 8; ++u) a = fmaf(wq1[t * 8 + u] * INV_SQRT8_F, ws1[u * 8 + v], a);
    C1[k] = a;
  }
}

__global__ void k_prep(const float* __restrict__ wk2, const float* __restrict__ wv2,
                       const float* __restrict__ wq0, const float* __restrict__ wq1,
                       const float* __restrict__ ws0, const float* __restrict__ ws1,
                       float* __restrict__ W2Tk, float* __restrict__ W2Tv,
                       u16t* __restrict__ W2Hk, u16t* __restrict__ W2Hv,
                       float* __restrict__ C0, float* __restrict__ C1) {
  int i = blockIdx.x * blockDim.x + threadIdx.x;
  prep_body(i, wk2, wv2, wq0, wq1, ws0, ws1, W2Tk, W2Tv, W2Hk, W2Hv, C0, C1);
}

// fused: hist (blocks < histBlocks) + prep (remaining blocks)
__global__ void k_hist_prep(const int* __restrict__ esrc, const int* __restrict__ edst,
                            int* __restrict__ cnt_s, int* __restrict__ cnt_d, int E,
                            int histBlocks,
                            const float* __restrict__ wk2, const float* __restrict__ wv2,
                            const float* __restrict__ wq0, const float* __restrict__ wq1,
                            const float* __restrict__ ws0, const float* __restrict__ ws1,
                            float* __restrict__ W2Tk, float* __restrict__ W2Tv,
                            u16t* __restrict__ W2Hk, u16t* __restrict__ W2Hv,
                            float* __restrict__ C0, float* __restrict__ C1) {
  if ((int)blockIdx.x < histBlocks) {
    int e = blockIdx.x * blockDim.x + threadIdx.x;
    if (e < E) {
      atomicAdd(&cnt_s[esrc[e]], 1);
      atomicAdd(&cnt_d[edst[e]], 1);
    }
  } else {
    int i = (blockIdx.x - histBlocks) * blockDim.x + threadIdx.x;
    prep_body(i, wk2, wv2, wq0, wq1, ws0, ws1, W2Tk, W2Tv, W2Hk, W2Hv, C0, C1);
  }
}

// node projection device body
__device__ __forceinline__ void node_body(int n, const float* __restrict__ x,
                                          const float* __restrict__ C0,
                                          const float* __restrict__ C1,
                                          float* __restrict__ qs0g,
                                          float* __restrict__ qs1g) {
  float xr[40];
  const float4* p = reinterpret_cast<const float4*>(x + (size_t)n * 40);
#pragma unroll
  for (int q = 0; q < 10; ++q) {
    float4 v = p[q];
    xr[q * 4 + 0] = v.x; xr[q * 4 + 1] = v.y; xr[q * 4 + 2] = v.z; xr[q * 4 + 3] = v.w;
  }
  float o0[16];
#pragma unroll
  for (int v = 0; v < 16; ++v) o0[v] = 0.f;
#pragma unroll
  for (int t = 0; t < 16; ++t) {
    float xt = xr[t];
    const float* c = C0 + t * 16;
#pragma unroll
    for (int v = 0; v < 16; ++v) o0[v] = fmaf(xt, c[v], o0[v]);
  }
  float4* q0p = reinterpret_cast<float4*>(qs0g + (size_t)n * 16);
#pragma unroll
  for (int q = 0; q < 4; ++q)
    q0p[q] = make_float4(o0[q * 4], o0[q * 4 + 1], o0[q * 4 + 2], o0[q * 4 + 3]);

  float o1[24];
#pragma unroll
  for (int v = 0; v < 24; ++v) o1[v] = 0.f;
#pragma unroll
  for (int u = 0; u < 8; ++u) {
    const float* c = C1 + u * 8;
    float xa = xr[16 + u * 3 + 0], xb = xr[16 + u * 3 + 1], xc = xr[16 + u * 3 + 2];
#pragma unroll
    for (int v = 0; v < 8; ++v) {
      float cv = c[v];
      o1[v * 3 + 0] = fmaf(xa, cv, o1[v * 3 + 0]);
      o1[v * 3 + 1] = fmaf(xb, cv, o1[v * 3 + 1]);
      o1[v * 3 + 2] = fmaf(xc, cv, o1[v * 3 + 2]);
    }
  }
  float4* q1p = reinterpret_cast<float4*>(qs1g + (size_t)n * 24);
#pragma unroll
  for (int q = 0; q < 6; ++q)
    q1p[q] = make_float4(o1[q * 4], o1[q * 4 + 1], o1[q * 4 + 2], o1[q * 4 + 3]);
}

__global__ void k_node(const float* __restrict__ x, const float* __restrict__ C0,
                       const float* __restrict__ C1, float* __restrict__ qs0g,
                       float* __restrict__ qs1g, int N) {
  int n = blockIdx.x * blockDim.x + threadIdx.x;
  if (n < N) node_body(n, x, C0, C1, qs0g, qs1g);
}

// ---------- CSR build ----------

__global__ void k_hist1(const int* __restrict__ key, int* __restrict__ cnt, int E) {
  int e = blockIdx.x * blockDim.x + threadIdx.x;
  if (e < E) atomicAdd(&cnt[key[e]], 1);
}

// fused: scan (blocks 0,1) + node projection (blocks 2+)
__global__ __launch_bounds__(1024) void k_scan_node(
    const int* __restrict__ cnt_s, int* __restrict__ off_s, int* __restrict__ cur_s,
    const int* __restrict__ cnt_d, int* __restrict__ off_d, int* __restrict__ cur_d,
    int N,
    const float* __restrict__ x, const float* __restrict__ C0,
    const float* __restrict__ C1, float* __restrict__ qs0g,
    float* __restrict__ qs1g) {
  __shared__ int ls[1024];
  if (blockIdx.x < 2) {
    const int* __restrict__ cnt = blockIdx.x ? cnt_d : cnt_s;
    int* __restrict__ off = blockIdx.x ? off_d : off_s;
    int* __restrict__ cur = blockIdx.x ? cur_d : cur_s;
    int tid = threadIdx.x;
    int per = (N + 1023) >> 10;
    int base = tid * per;
    int sum = 0;
    for (int j = 0; j < per; ++j) {
      int idx = base + j;
      if (idx < N) sum += cnt[idx];
    }
    ls[tid] = sum;
    __syncthreads();
    for (int d = 1; d < 1024; d <<= 1) {
      int v = (tid >= d) ? ls[tid - d] : 0;
      __syncthreads();
      ls[tid] += v;
      __syncthreads();
    }
    int run = ls[tid] - sum;
    for (int j = 0; j < per; ++j) {
      int idx = base + j;
      if (idx < N) {
        off[idx] = run;
        cur[idx] = run;
        run += cnt[idx];
      }
    }
    if (tid == 1023) off[N] = run;
  } else {
    int n = (blockIdx.x - 2) * 1024 + threadIdx.x;
    if (n < N) node_body(n, x, C0, C1, qs0g, qs1g);
  }
}

// general scan (fallback path)
__global__ __launch_bounds__(1024) void k_scan2(const int* __restrict__ cnt_s,
                                                int* __restrict__ off_s,
                                                int* __restrict__ cur_s,
                                                const int* __restrict__ cnt_d,
                                                int* __restrict__ off_d,
                                                int* __restrict__ cur_d, int N) {
  const int* __restrict__ cnt = blockIdx.x ? cnt_d : cnt_s;
  int* __restrict__ off = blockIdx.x ? off_d : off_s;
  int* __restrict__ cur = blockIdx.x ? cur_d : cur_s;
  __shared__ int ls[1024];
  int tid = threadIdx.x;
  int per = (N + 1023) >> 10;
  int base = tid * per;
  int sum = 0;
  for (int j = 0; j < per; ++j) {
    int idx = base + j;
    if (idx < N) sum += cnt[idx];
  }
  ls[tid] = sum;
  __syncthreads();
  for (int d = 1; d < 1024; d <<= 1) {
    int v = (tid >= d) ? ls[tid - d] : 0;
    __syncthreads();
    ls[tid] += v;
    __syncthreads();
  }
  int run = ls[tid] - sum;
  for (int j = 0; j < per; ++j) {
    int idx = base + j;
    if (idx < N) {
      off[idx] = run;
      cur[idx] = run;
      run += cnt[idx];
    }
  }
  if (tid == 1023) off[N] = run;
}

// place: write sorted (src,dst) edge arrays + dst-order position list
__global__ void k_place3(const int* __restrict__ esrc, const int* __restrict__ edst,
                         int* __restrict__ cur_s, int* __restrict__ cur_d,
                         int* __restrict__ es2, int* __restrict__ ed2,
                         int* __restrict__ idx, int E) {
  int e = blockIdx.x * blockDim.x + threadIdx.x;
  if (e < E) {
    int s = esrc[e], d = edst[e];
    int p = atomicAdd(&cur_s[s], 1);
    es2[p] = s;
    ed2[p] = d;
    int q = atomicAdd(&cur_d[d], 1);
    idx[q] = p;
  }
}

__global__ void k_place(const int* __restrict__ key, int* __restrict__ cursor,
                        int* __restrict__ perm, int E) {
  int e = blockIdx.x * blockDim.x + threadIdx.x;
  if (e < E) {
    int p = atomicAdd(&cursor[key[e]], 1);
    perm[p] = e;
  }
}

// ---------- fused table-gen + edge kernel (f16 tables + fdot2, chunked) ----------

__global__ __launch_bounds__(TPBF) void k_fused(
    const float* __restrict__ x, const float* __restrict__ pos,
    const int* __restrict__ es2, const int* __restrict__ ed2,
    const int* __restrict__ off_s,
    const float* __restrict__ W1k, const u16t* __restrict__ W2Hk,
    const float* __restrict__ W1v, const u16t* __restrict__ W2Hv,
    const float* __restrict__ qs0g, const float* __restrict__ qs1g,
    float* __restrict__ s_out, u16t* __restrict__ stg, int N) {
  __shared__ __align__(16) u16t tl[SRCS_PER_GRP * SRC_STRIDE_U16];
  __shared__ unsigned xh[SRCS_PER_GRP * 40];   // f16x2 splats of x rows
  int tid = threadIdx.x;
  int base = blockIdx.x * SRCS_PER_GRP;
  int nsrc = min(SRCS_PER_GRP, N - base);
  int glo = off_s[base], ghi = off_s[base + nsrc];

  // stage x rows as f16 splats
  for (int idx = tid; idx < nsrc * 40; idx += TPBF) {
    int s = idx / 40, u = idx - s * 40;
    float v = x[(size_t)(base + s) * 40 + u];
    f16x2 hh; hh.x = (_Float16)v; hh.y = hh.x;
    xh[s * 40 + u] = f16x2_bits(hh);
  }
  __syncthreads();

  // KEY tables
  gen_tables(W2Hk, xh, tl, nsrc, tid);
  __syncthreads();

  for (int p0 = glo; p0 < ghi; p0 += TPBF) {
    int p = p0 + tid;
    bool act = p < ghi;

    // per-edge state carried across the LDS table swap (registers)
    float shx = 0.f, shy = 0.f, shz = 0.f;
    int sloc = 0;
    f16x2 hvp[8];
#pragma unroll
    for (int j = 0; j < 8; ++j) { hvp[j].x = (_Float16)0.f; hvp[j].y = (_Float16)0.f; }

    if (act) {
      int src = es2[p];
      int dst = ed2[p];
      sloc = src - base;
      float hk[16], hv[16];
      compute_h2s(pos, W1k, W1v, src, dst, shx, shy, shz, hk, hv);
      f16x2 hkp[8];
      pack_h16(hk, hkp);
      pack_h16(hv, hvp);

      const u16t* tk = &tl[sloc * SRC_STRIDE_U16];
      // ---- key: similarity ----
      const float4* q0p = reinterpret_cast<const float4*>(qs0g + (size_t)dst * 16);
      float S0 = 0.f;
#pragma unroll 2
      for (int w4 = 0; w4 < 4; ++w4) {
        float4 qq = q0p[w4];
        float q[4] = {qq.x, qq.y, qq.z, qq.w};
#pragma unroll
        for (int k = 0; k < 4; ++k) {
          float t0 = dotjh(tk + (w4 * 4 + k) * 16, hkp);
          float t3x = dotjh(tk + (48 + w4 * 12 + k * 3 + 0) * 16, hkp);
          float t3y = dotjh(tk + (48 + w4 * 12 + k * 3 + 1) * 16, hkp);
          float t3z = dotjh(tk + (48 + w4 * 12 + k * 3 + 2) * 16, hkp);
          S0 = fmaf(q[k], fmaf(INV3_F, t3x * shx + t3y * shy + t3z * shz, t0), S0);
        }
      }
      const float4* q1p = reinterpret_cast<const float4*>(qs1g + (size_t)dst * 24);
      float S1 = 0.f;
#pragma unroll 2
      for (int w4 = 0; w4 < 2; ++w4) {
        float4 qa = q1p[w4 * 3 + 0];
        float4 qb = q1p[w4 * 3 + 1];
        float4 qc = q1p[w4 * 3 + 2];
        float q[12] = {qa.x, qa.y, qa.z, qa.w, qb.x, qb.y, qb.z, qb.w,
                       qc.x, qc.y, qc.z, qc.w};
#pragma unroll
        for (int k = 0; k < 4; ++k) {
          float qx = q[k * 3 + 0], qy = q[k * 3 + 1], qz = q[k * 3 + 2];
          float t1 = dotjh(tk + (16 + w4 * 4 + k) * 16, hkp);
          float t2x = dotjh(tk + (24 + w4 * 12 + k * 3 + 0) * 16, hkp);
          float t2y = dotjh(tk + (24 + w4 * 12 + k * 3 + 1) * 16, hkp);
          float t2z = dotjh(tk + (24 + w4 * 12 + k * 3 + 2) * 16, hkp);
          float c0 = dotjh(tk + (96 + w4 * 12 + k * 3 + 0) * 16, hkp);
          float c1 = dotjh(tk + (96 + w4 * 12 + k * 3 + 1) * 16, hkp);
          float c2 = dotjh(tk + (96 + w4 * 12 + k * 3 + 2) * 16, hkp);
          float crx = c1 * shz - c2 * shy;
          float cry = c2 * shx - c0 * shz;
          float crz = c0 * shy - c1 * shx;
          float qdots = qx * shx + qy * shy + qz * shz;
          S1 += INV3_F * (t1 * qdots + t2x * qx + t2y * qy + t2z * qz) +
                INV6_F * (crx * qx + cry * qy + crz * qz);
        }
      }
      s_out[p] = PWSIM_F * (PW0_F * S0 + PW1_F * INV3_F * S1);
    }
    __syncthreads();

    // VALUE tables (overwrite LDS)
    gen_tables(W2Hv, xh, tl, nsrc, tid);
    __syncthreads();

    if (act) {
      const u16t* tv = &tl[sloc * SRC_STRIDE_U16];
      u16t* sp = stg + (size_t)p * 40;
#pragma unroll 2
      for (int w4 = 0; w4 < 4; ++w4) {
        float f[4];
#pragma unroll
        for (int k = 0; k < 4; ++k) {
          float t0 = dotjh(tv + (w4 * 4 + k) * 16, hvp);
          float t3x = dotjh(tv + (48 + w4 * 12 + k * 3 + 0) * 16, hvp);
          float t3y = dotjh(tv + (48 + w4 * 12 + k * 3 + 1) * 16, hvp);
          float t3z = dotjh(tv + (48 + w4 * 12 + k * 3 + 2) * 16, hvp);
          f[k] = PW0_F * fmaf(INV3_F, t3x * shx + t3y * shy + t3z * shz, t0);
        }
        f16x2 pa; pa.x = (_Float16)f[0]; pa.y = (_Float16)f[1];
        f16x2 pb; pb.x = (_Float16)f[2]; pb.y = (_Float16)f[3];
        int2 pk;
        pk.x = (int)f16x2_bits(pa);
        pk.y = (int)f16x2_bits(pb);
        *reinterpret_cast<int2*>(sp + w4 * 4) = pk;
      }
#pragma unroll 2
      for (int w4 = 0; w4 < 2; ++w4) {
        float f[12];
#pragma unroll
        for (int k = 0; k < 4; ++k) {
          float t1 = dotjh(tv + (16 + w4 * 4 + k) * 16, hvp);
          float t2x = dotjh(tv + (24 + w4 * 12 + k * 3 + 0) * 16, hvp);
          float t2y = dotjh(tv + (24 + w4 * 12 + k * 3 + 1) * 16, hvp);
          float t2z = dotjh(tv + (24 + w4 * 12 + k * 3 + 2) * 16, hvp);
          float c0 = dotjh(tv + (96 + w4 * 12 + k * 3 + 0) * 16, hvp);
          float c1 = dotjh(tv + (96 + w4 * 12 + k * 3 + 1) * 16, hvp);
          float c2 = dotjh(tv + (96 + w4 * 12 + k * 3 + 2) * 16, hvp);
          float crx = c1 * shz - c2 * shy;
          float cry = c2 * shx - c0 * shz;
          float crz = c0 * shy - c1 * shx;
          f[k * 3 + 0] = PW1_F * (INV3_F * fmaf(t1, shx, t2x) + INV6_F * crx);
          f[k * 3 + 1] = PW1_F * (INV3_F * fmaf(t1, shy, t2y) + INV6_F * cry);
          f[k * 3 + 2] = PW1_F * (INV3_F * fmaf(t1, shz, t2z) + INV6_F * crz);
        }
#pragma unroll
        for (int g = 0; g < 3; ++g) {
          f16x2 pa; pa.x = (_Float16)f[g * 4 + 0]; pa.y = (_Float16)f[g * 4 + 1];
          f16x2 pb; pb.x = (_Float16)f[g * 4 + 2]; pb.y = (_Float16)f[g * 4 + 3];
          int2 pk;
          pk.x = (int)f16x2_bits(pa);
          pk.y = (int)f16x2_bits(pb);
          *reinterpret_cast<int2*>(sp + 16 + w4 * 12 + g * 4) = pk;
        }
      }
    }

    if (p0 + TPBF < ghi) {   // more chunks: restore KEY tables
      __syncthreads();
      gen_tables(W2Hk, xh, tl, nsrc, tid);
      __syncthreads();
    }
  }
}

// ---------- fused per-node softmax + gather (shuffle-shared coef) ----------

__global__ void k_smg(const float* __restrict__ s, const u16t* __restrict__ stg,
                      const int* __restrict__ off, const int* __restrict__ idx,
                      float* __restrict__ out, int N) {
  int gid = blockIdx.x * blockDim.x + threadIdx.x;
  int wid = gid >> 6;
  int lane = threadIdx.x & 63;
  if (wid >= N) return;
  int lo = off[wid], hi = off[wid + 1];
  float m = -1e30f;
  for (int q = lo + lane; q < hi; q += 64) m = fmaxf(m, s[idx[q]]);
#pragma unroll
  for (int d = 32; d; d >>= 1) m = fmaxf(m, __shfl_xor(m, d));
  float sum = 0.f;
  for (int q = lo + lane; q < hi; q += 64) sum += __expf(s[idx[q]] - m);
#pragma unroll
  for (int d = 32; d; d >>= 1) sum += __shfl_xor(sum, d);
  float inv = 1.0f / sum;
  float acc = 0.f;
  for (int q0 = lo; q0 < hi; q0 += 64) {
    int q = q0 + lane;
    int pv = 0;
    float cv = 0.f;
    if (q < hi) {
      pv = idx[q];
      cv = sqrtf(__expf(s[pv] - m) * inv);
    }
    int nj = min(64, hi - q0);
    for (int j = 0; j < nj; ++j) {
      float cj = __shfl(cv, j);
      int pj = __shfl(pv, j);
      if (lane < 40)
        acc = fmaf(cj, f16b2f(stg[(size_t)pj * 40 + lane]), acc);
    }
  }
  if (lane < 40) out[(size_t)wid * 40 + lane] = acc;
}

// ---------- fallback (round-2) fused edge kernel, fp32 staging ----------

__global__ __launch_bounds__(TPB) void k_edge_fused(
    const float* __restrict__ x, const float* __restrict__ pos,
    const int* __restrict__ esrc, const int* __restrict__ edst,
    const int* __restrict__ perm,
    const float* __restrict__ W1k, const float* __restrict__ W2Tk,
    const float* __restrict__ W1v, const float* __restrict__ W2Tv,
    const float* __restrict__ qs0g, const float* __restrict__ qs1g,
    float* __restrict__ s_out, float* __restrict__ staging, int E) {
  __shared__ float xs[TPB * 41];
  int p = blockIdx.x * TPB + threadIdx.x;
  if (p >= E) return;
  int e = perm[p];
  int src = esrc[e], dst = edst[e];

  float* myx = &xs[threadIdx.x * 41];
  const float4* xrow = reinterpret_cast<const float4*>(x + (size_t)src * 40);
#pragma unroll
  for (int q = 0; q < 10; ++q) {
    float4 v = xrow[q];
    myx[q * 4 + 0] = v.x; myx[q * 4 + 1] = v.y; myx[q * 4 + 2] = v.z; myx[q * 4 + 3] = v.w;
  }

  float sh1[3], hk[16], hv[16];
  compute_h2s(pos, W1k, W1v, src, dst, sh1[0], sh1[1], sh1[2], hk, hv);

  {
    float qs0[16];
    {
      const float4* qp = reinterpret_cast<const float4*>(qs0g + (size_t)dst * 16);
#pragma unroll
      for (int q = 0; q < 4; ++q) {
        float4 v = qp[q];
        qs0[q * 4 + 0] = v.x; qs0[q * 4 + 1] = v.y; qs0[q * 4 + 2] = v.z; qs0[q * 4 + 3] = v.w;
      }
    }
    float qs1[24];
    {
      const float4* qp = reinterpret_cast<const float4*>(qs1g + (size_t)dst * 24);
#pragma unroll
      for (int q = 0; q < 6; ++q) {
        float4 v = qp[q];
        qs1[q * 4 + 0] = v.x; qs1[q * 4 + 1] = v.y; qs1[q * 4 + 2] = v.z; qs1[q * 4 + 3] = v.w;
      }
    }
    float qsh[8];
#pragma unroll
    for (int w = 0; w < 8; ++w)
      qsh[w] = qs1[w * 3] * sh1[0] + qs1[w * 3 + 1] * sh1[1] + qs1[w * 3 + 2] * sh1[2];

    float S0a = 0.f, S0b = 0.f, S1a = 0.f, S1b = 0.f, S1c = 0.f;
#pragma unroll 1
    for (int u = 0; u < 16; ++u) {
      const float* base = W2Tk + (u * 16) * 16;
      float accu = 0.f;
#pragma unroll
      for (int w = 0; w < 16; ++w) accu = fmaf(dot16u(base + w * 16, hk), qs0[w], accu);
      S0a = fmaf(accu, myx[u], S0a);
    }
#pragma unroll 1
    for (int u = 0; u < 16; ++u) {
      const float* base = W2Tk + (256 + u * 8) * 16;
      float accu = 0.f;
#pragma unroll
      for (int w = 0; w < 8; ++w) accu = fmaf(dot16u(base + w * 16, hk), qsh[w], accu);
      S1a = fmaf(accu, myx[u], S1a);
    }
#pragma unroll 1
    for (int u = 0; u < 8; ++u) {
      const float* base = W2Tk + (384 + u * 8) * 16;
      float x1a = myx[16 + u * 3 + 0], x1b = myx[16 + u * 3 + 1], x1c = myx[16 + u * 3 + 2];
      float accu = 0.f;
#pragma unroll
      for (int w = 0; w < 8; ++w) {
        float t = qs1[w * 3] * x1a + qs1[w * 3 + 1] * x1b + qs1[w * 3 + 2] * x1c;
        accu = fmaf(dot16u(base + w * 16, hk), t, accu);
      }
      S1b += accu;
    }
#pragma unroll 1
    for (int u = 0; u < 8; ++u) {
      const float* base = W2Tk + (448 + u * 16) * 16;
      float x1a = myx[16 + u * 3 + 0], x1b = myx[16 + u * 3 + 1], x1c = myx[16 + u * 3 + 2];
      float du = x1a * sh1[0] + x1b * sh1[1] + x1c * sh1[2];
      float accu = 0.f;
#pragma unroll
      for (int w = 0; w < 16; ++w) accu = fmaf(dot16u(base + w * 16, hk), qs0[w], accu);
      S0b = fmaf(accu, du, S0b);
    }
#pragma unroll 1
    for (int u = 0; u < 8; ++u) {
      const float* base = W2Tk + (576 + u * 8) * 16;
      float x1a = myx[16 + u * 3 + 0], x1b = myx[16 + u * 3 + 1], x1c = myx[16 + u * 3 + 2];
      float cx = x1b * sh1[2] - x1c * sh1[1];
      float cy = x1c * sh1[0] - x1a * sh1[2];
      float cz = x1a * sh1[1] - x1b * sh1[0];
      float accu = 0.f;
#pragma unroll
      for (int w = 0; w < 8; ++w) {
        float t = qs1[w * 3] * cx + qs1[w * 3 + 1] * cy + qs1[w * 3 + 2] * cz;
        accu = fmaf(dot16u(base + w * 16, hk), t, accu);
      }
      S1c += accu;
    }
    s_out[p] = PWSIM_F * (PW0_F * (S0a + INV3_F * S0b) +
                          (INV3_F * PW1_F) * (INV3_F * S1a + INV3_F * S1b + INV6_F * S1c));
  }

  float v0[16];
#pragma unroll
  for (int w = 0; w < 16; ++w) v0[w] = 0.f;
  float v1[24];
#pragma unroll
  for (int w = 0; w < 24; ++w) v1[w] = 0.f;

#pragma unroll 1
  for (int u = 0; u < 16; ++u) {
    const float* base = W2Tv + (u * 16) * 16;
    float xu = myx[u];
#pragma unroll
    for (int w = 0; w < 16; ++w) v0[w] = fmaf(dot16u(base + w * 16, hv), xu, v0[w]);
  }
  {
    float aw[8];
#pragma unroll
    for (int w = 0; w < 8; ++w) aw[w] = 0.f;
#pragma unroll 1
    for (int u = 0; u < 16; ++u) {
      const float* base = W2Tv + (256 + u * 8) * 16;
      float xu = myx[u];
#pragma unroll
      for (int w = 0; w < 8; ++w) aw[w] = fmaf(dot16u(base + w * 16, hv), xu, aw[w]);
    }
#pragma unroll
    for (int w = 0; w < 8; ++w) {
      float t = INV3_F * aw[w];
      v1[w * 3 + 0] = fmaf(t, sh1[0], v1[w * 3 + 0]);
      v1[w * 3 + 1] = fmaf(t, sh1[1], v1[w * 3 + 1]);
      v1[w * 3 + 2] = fmaf(t, sh1[2], v1[w * 3 + 2]);
    }
  }
#pragma unroll 1
  for (int u = 0; u < 8; ++u) {
    const float* base = W2Tv + (384 + u * 8) * 16;
    float a0 = INV3_F * myx[16 + u * 3 + 0];
    float a1 = INV3_F * myx[16 + u * 3 + 1];
    float a2 = INV3_F * myx[16 + u * 3 + 2];
#pragma unroll
    for (int w = 0; w < 8; ++w) {
      float wk = dot16u(base + w * 16, hv);
      v1[w * 3 + 0] = fmaf(wk, a0, v1[w * 3 + 0]);
      v1[w * 3 + 1] = fmaf(wk, a1, v1[w * 3 + 1]);
      v1[w * 3 + 2] = fmaf(wk, a2, v1[w * 3 + 2]);
    }
  }
#pragma unroll 1
  for (int u = 0; u < 8; ++u) {
    const float* base = W2Tv + (448 + u * 16) * 16;
    float x1a = myx[16 + u * 3 + 0], x1b = myx[16 + u * 3 + 1], x1c = myx[16 + u * 3 + 2];
    float du = INV3_F * (x1a * sh1[0] + x1b * sh1[1] + x1c * sh1[2]);
#pragma unroll
    for (int w = 0; w < 16; ++w) v0[w] = fmaf(dot16u(base + w * 16, hv), du, v0[w]);
  }
#pragma unroll 1
  for (int u = 0; u < 8; ++u) {
    const float* base = W2Tv + (576 + u * 8) * 16;
    float x1a = myx[16 + u * 3 + 0], x1b = myx[16 + u * 3 + 1], x1c = myx[16 + u * 3 + 2];
    float cx = INV6_F * (x1b * sh1[2] - x1c * sh1[1]);
    float cy = INV6_F * (x1c * sh1[0] - x1a * sh1[2]);
    float cz = INV6_F * (x1a * sh1[1] - x1b * sh1[0]);
#pragma unroll
    for (int w = 0; w < 8; ++w) {
      float wk = dot16u(base + w * 16, hv);
      v1[w * 3 + 0] = fmaf(wk, cx, v1[w * 3 + 0]);
      v1[w * 3 + 1] = fmaf(wk, cy, v1[w * 3 + 1]);
      v1[w * 3 + 2] = fmaf(wk, cz, v1[w * 3 + 2]);
    }
  }

  float outv[40];
#pragma unroll
  for (int w = 0; w < 16; ++w) outv[w] = PW0_F * v0[w];
#pragma unroll
  for (int w = 0; w < 24; ++w) outv[16 + w] = PW1_F * v1[w];
  float4* st = reinterpret_cast<float4*>(staging + (size_t)p * 40);
#pragma unroll
  for (int q = 0; q < 10; ++q)
    st[q] = make_float4(outv[q * 4], outv[q * 4 + 1], outv[q * 4 + 2], outv[q * 4 + 3]);
}

__global__ void k_softmax(const float* __restrict__ s, const int* __restrict__ off,
                          float* __restrict__ coef, int N) {
  int gid = blockIdx.x * blockDim.x + threadIdx.x;
  int wid = gid >> 6;
  int lane = threadIdx.x & 63;
  if (wid >= N) return;
  int lo = off[wid], hi = off[wid + 1];
  float m = -1e30f;
  for (int p = lo + lane; p < hi; p += 64) m = fmaxf(m, s[p]);
#pragma unroll
  for (int d = 32; d; d >>= 1) m = fmaxf(m, __shfl_xor(m, d));
  float sum = 0.f;
  for (int p = lo + lane; p < hi; p += 64) sum += __expf(s[p] - m);
#pragma unroll
  for (int d = 32; d; d >>= 1) sum += __shfl_xor(sum, d);
  float inv = 1.0f / sum;
  for (int p = lo + lane; p < hi; p += 64)
    coef[p] = sqrtf(__expf(s[p] - m) * inv);
}

__global__ void k_gather(const float* __restrict__ staging, const float* __restrict__ coef,
                         const int* __restrict__ off, float* __restrict__ out, int N) {
  int gid = blockIdx.x * blockDim.x + threadIdx.x;
  int wid = gid >> 6;
  int lane = threadIdx.x & 63;
  if (wid >= N) return;
  int lo = off[wid], hi = off[wid + 1];
  if (lane < 40) {
    float acc = 0.f;
    for (int p = lo; p < hi; ++p)
      acc = fmaf(coef[p], staging[(size_t)p * 40 + lane], acc);
    out[(size_t)wid * 40 + lane] = acc;
  }
}

// ---------- host launcher ----------

extern "C" void kernel_launch(void* const* d_in, const int* in_sizes, int n_in,
                              void* d_out, int out_size, void* d_ws, size_t ws_size,
                              hipStream_t stream) {
  const float* x   = (const float*)d_in[0];
  const float* pos = (const float*)d_in[1];
  const int* esrc  = (const int*)d_in[2];
  const int* edst  = (const int*)d_in[3];
  const float* wk1 = (const float*)d_in[4];
  const float* wk2 = (const float*)d_in[5];
  const float* wv1 = (const float*)d_in[6];
  const float* wv2 = (const float*)d_in[7];
  const float* wq0 = (const float*)d_in[8];
  const float* wq1 = (const float*)d_in[9];
  const float* ws0 = (const float*)d_in[10];
  const float* ws1 = (const float*)d_in[11];

  int E = in_sizes[2];
  int N = in_sizes[0] / 40;

  float* ws = (float*)d_ws;
  float* W2Tk = ws;                        // 10240 f32
  float* W2Tv = ws + 10240;                // 10240 f32
  float* C0   = ws + 20480;                // 256
  float* C1   = ws + 20736;                // 64
  u16t* W2Hk  = (u16t*)(ws + 20800);       // 10240 u16
  u16t* W2Hv  = W2Hk + 10240;              // 10240 u16
  float* qs0g = ws + 20800 + 10240;        // N*16  (20480 u16 = 10240 f32)
  float* qs1g = qs0g + (size_t)N * 16;     // N*24
  float* base2 = qs1g + (size_t)N * 24;

  // fast-path layout
  float* s_ws = base2;                                  // E
  int* cnt_s  = (int*)(s_ws + (size_t)E);               // N
  int* cnt_d  = cnt_s + N;                              // N
  int* off_s  = cnt_d + N;                              // N+1
  int* cur_s  = off_s + N + 1;                          // N
  int* off_d  = cur_s + N;                              // N+1
  int* cur_d  = off_d + N + 1;                          // N
  int* es2    = cur_d + N;                              // E
  int* ed2    = es2 + (size_t)E;                        // E
  int* idxd   = ed2 + (size_t)E;                        // E
  u16t* stgb  = (u16t*)(idxd + (size_t)E);              // E*40 u16
  size_t need_fast = (size_t)((char*)(stgb + (size_t)E * 40) - (char*)d_ws);

  if (ws_size >= need_fast) {
    hipMemsetAsync(cnt_s, 0, sizeof(int) * (size_t)(2 * N), stream);
    int histBlocks = (E + 255) / 256;
    int prepBlocks = (20800 + 255) / 256;
    k_hist_prep<<<histBlocks + prepBlocks, 256, 0, stream>>>(
        esrc, edst, cnt_s, cnt_d, E, histBlocks,
        wk2, wv2, wq0, wq1, ws0, ws1, W2Tk, W2Tv, W2Hk, W2Hv, C0, C1);
    int nodeBlocks = (N + 1023) / 1024;
    k_scan_node<<<2 + nodeBlocks, 1024, 0, stream>>>(
        cnt_s, off_s, cur_s, cnt_d, off_d, cur_d, N, x, C0, C1, qs0g, qs1g);
    k_place3<<<(E + 255) / 256, 256, 0, stream>>>(esrc, edst, cur_s, cur_d,
                                                  es2, ed2, idxd, E);
    int ng = (N + SRCS_PER_GRP - 1) / SRCS_PER_GRP;
    k_fused<<<ng, TPBF, 0, stream>>>(x, pos, es2, ed2, off_s,
                                     wk1, W2Hk, wv1, W2Hv, qs0g, qs1g,
                                     s_ws, stgb, N);
    k_smg<<<((N * 64) + 255) / 256, 256, 0, stream>>>(s_ws, stgb, off_d, idxd,
                                                      (float*)d_out, N);
  } else {
    // fallback: round-2 dst-sorted fp32-staging path
    float* coefF = s_ws + (size_t)E;                    // E (reuse area)
    int* cnt    = (int*)(coefF + (size_t)E);            // N
    int* off    = cnt + N;                              // N+1
    int* cursor = off + N + 1;                          // N
    int* permF  = cursor + N;                           // E
    float* staging = (float*)(permF + (size_t)E);       // E*40

    k_prep<<<(20800 + 255) / 256, 256, 0, stream>>>(wk2, wv2, wq0, wq1, ws0, ws1,
                                                    W2Tk, W2Tv, W2Hk, W2Hv, C0, C1);
    k_node<<<(N + 255) / 256, 256, 0, stream>>>(x, C0, C1, qs0g, qs1g, N);
    hipMemsetAsync(cnt, 0, sizeof(int) * (size_t)N, stream);
    k_hist1<<<(E + 255) / 256, 256, 0, stream>>>(edst, cnt, E);
    k_scan2<<<1, 1024, 0, stream>>>(cnt, off, cursor, cnt, off, cursor, N);
    k_place<<<(E + 255) / 256, 256, 0, stream>>>(edst, cursor, permF, E);
    k_edge_fused<<<(E + TPB - 1) / TPB, TPB, 0, stream>>>(
        x, pos, esrc, edst, permF, wk1, W2Tk, wv1, W2Tv, qs0g, qs1g,
        s_ws, staging, E);
    k_softmax<<<((N * 64) + 255) / 256, 256, 0, stream>>>(s_ws, off, coefF, N);
    k_gather<<<((N * 64) + 255) / 256, 256, 0, stream>>>(staging, coefF, off,
                                                         (float*)d_out, N);
  }
}

// Round 21
// 230.217 us; speedup vs baseline: 1.1329x; 1.1329x over previous
//
#include <hip/hip_runtime.h>
#include <math.h>

#define TPB 256
#define TPBF 256               // fused edge kernel block (4 waves — measured occupancy optimum: 192->27%, 256->35%, 384->29%)
#define SRCS_PER_GRP 8
#define SRC_STRIDE_U16 1928    // 3856B/src, 16B-aligned per src, bank-spread

#define RMAX_F 2.5f
#define PI_F 3.14159265358979323846f
#define SQRT3_F 1.7320508075688772f
#define INV3_F 0.5773502691896258f
#define INV6_F 0.4082482904638631f
#define PW0_F 0.2041241452319315f
#define PW1_F 0.3061862178478972f
#define PWSIM_F 0.05590169943749474f
#define SILU_C_F 1.676866f
#define RB_F 0.8944271909999159f
#define INV_SQRT8_F 0.35355339059327373f

typedef unsigned short u16t;
typedef _Float16 f16x2 __attribute__((ext_vector_type(2)));

#if defined(__has_builtin)
#if __has_builtin(__builtin_amdgcn_fdot2)
#define HAVE_FDOT2 1
#else
#define HAVE_FDOT2 0
#endif
#else
#define HAVE_FDOT2 0
#endif

// ---------- helpers ----------

__device__ __forceinline__ f16x2 as_f16x2(int v) {
  union { int i; f16x2 h; } u; u.i = v; return u.h;
}
__device__ __forceinline__ unsigned f16x2_bits(f16x2 h) {
  union { f16x2 h; unsigned u; } c; c.h = h; return c.u;
}
__device__ __forceinline__ float f16b2f(u16t b) {
  union { u16t u; _Float16 h; } c; c.u = b; return (float)c.h;
}

__device__ __forceinline__ float dot2f16(f16x2 a, f16x2 b, float c) {
#if HAVE_FDOT2
  return __builtin_amdgcn_fdot2(a, b, c, false);
#else
  return fmaf((float)a.x, (float)b.x, fmaf((float)a.y, (float)b.y, c));
#endif
}

// dot of 16 f16 entries (contiguous, 16B-aligned; LDS) with packed f16 h
__device__ __forceinline__ float dotjh(const u16t* __restrict__ t,
                                       const f16x2* __restrict__ hp) {
  const int4* q = reinterpret_cast<const int4*>(t);
  int4 a = q[0], b = q[1];
  float s0 = 0.f, s1 = 0.f;
  s0 = dot2f16(as_f16x2(a.x), hp[0], s0);
  s1 = dot2f16(as_f16x2(a.y), hp[1], s1);
  s0 = dot2f16(as_f16x2(a.z), hp[2], s0);
  s1 = dot2f16(as_f16x2(a.w), hp[3], s1);
  s0 = dot2f16(as_f16x2(b.x), hp[4], s0);
  s1 = dot2f16(as_f16x2(b.y), hp[5], s1);
  s0 = dot2f16(as_f16x2(b.z), hp[6], s0);
  s1 = dot2f16(as_f16x2(b.w), hp[7], s1);
  return s0 + s1;
}

__device__ __forceinline__ void pack_h16(const float* __restrict__ h,
                                         f16x2* __restrict__ hp) {
#pragma unroll
  for (int i = 0; i < 8; ++i) {
    f16x2 v;
    v.x = (_Float16)h[2 * i + 0];
    v.y = (_Float16)h[2 * i + 1];
    hp[i] = v;
  }
}

// fallback-path helper (fp32)
__device__ __forceinline__ float dot16u(const float* __restrict__ w, const float* __restrict__ h) {
  float a0 = 0.f, a1 = 0.f, a2 = 0.f, a3 = 0.f;
#pragma unroll
  for (int j = 0; j < 16; j += 4) {
    a0 = fmaf(h[j + 0], w[j + 0], a0);
    a1 = fmaf(h[j + 1], w[j + 1], a1);
    a2 = fmaf(h[j + 2], w[j + 2], a2);
    a3 = fmaf(h[j + 3], w[j + 3], a3);
  }
  return (a0 + a1) + (a2 + a3);
}

// both nets, shared sin chain
__device__ __forceinline__ void compute_h2s(const float* __restrict__ pos,
                                            const float* __restrict__ W1k,
                                            const float* __restrict__ W1v,
                                            int src, int dst,
                                            float& shx, float& shy, float& shz,
                                            float hk[16], float hv[16]) {
  float vx = pos[3 * src + 0] - pos[3 * dst + 0];
  float vy = pos[3 * src + 1] - pos[3 * dst + 1];
  float vz = pos[3 * src + 2] - pos[3 * dst + 2];
  float r2 = fmaf(vx, vx, fmaf(vy, vy, vz * vz)) + 1e-12f;
  float r = sqrtf(r2);
  float inv_r = 1.0f / r;
  shx = SQRT3_F * vx * inv_r;
  shy = SQRT3_F * vy * inv_r;
  shz = SQRT3_F * vz * inv_r;
  float f = (r < RMAX_F) ? (RB_F * inv_r) : 0.0f;
  float t0 = (PI_F / RMAX_F) * r;
  float s1, c1;
  __sincosf(t0, &s1, &c1);
  float c2 = 2.0f * c1;
  float sm = 0.0f, sc = s1;
  float ak[16], av[16];
#pragma unroll
  for (int j = 0; j < 16; ++j) { ak[j] = 0.0f; av[j] = 0.0f; }
#pragma unroll 2
  for (int n = 0; n < 32; ++n) {
    float rb = f * sc;
    const float* wk = W1k + n * 16;
    const float* wv = W1v + n * 16;
#pragma unroll
    for (int j = 0; j < 16; ++j) ak[j] = fmaf(rb, wk[j], ak[j]);
#pragma unroll
    for (int j = 0; j < 16; ++j) av[j] = fmaf(rb, wv[j], av[j]);
    float nx = fmaf(c2, sc, -sm);
    sm = sc; sc = nx;
  }
#pragma unroll
  for (int j = 0; j < 16; ++j) {
    float v = ak[j];
    hk[j] = SILU_C_F * v * (1.0f / (1.0f + __expf(-v)));
    float w = av[j];
    hv[j] = SILU_C_F * w * (1.0f / (1.0f + __expf(-w)));
  }
}

// f16-packed table entry: acc over u of xh[u] (splat) * W2H row (8 f16x2)
__device__ __forceinline__ void gen_entry_h(const u16t* __restrict__ W2H,
                                            const unsigned* __restrict__ xh,
                                            int mm, unsigned outw[8]) {
  f16x2 acc[8];
#pragma unroll
  for (int i = 0; i < 8; ++i) { acc[i].x = (_Float16)0.f; acc[i].y = (_Float16)0.f; }
  if (mm < 16) {
    int w = mm;
#pragma unroll 1
    for (int u = 0; u < 16; ++u) {
      f16x2 xv = as_f16x2((int)xh[u]);
      const f16x2* wp = reinterpret_cast<const f16x2*>(W2H + (u * 16 + w) * 16);
#pragma unroll
      for (int i = 0; i < 8; ++i) acc[i] += xv * wp[i];
    }
  } else if (mm < 24) {
    int w = mm - 16;
#pragma unroll 1
    for (int u = 0; u < 16; ++u) {
      f16x2 xv = as_f16x2((int)xh[u]);
      const f16x2* wp = reinterpret_cast<const f16x2*>(W2H + (256 + u * 8 + w) * 16);
#pragma unroll
      for (int i = 0; i < 8; ++i) acc[i] += xv * wp[i];
    }
  } else if (mm < 48) {
    int tt = mm - 24, w = tt / 3, i3 = tt - w * 3;
#pragma unroll 1
    for (int u = 0; u < 8; ++u) {
      f16x2 xv = as_f16x2((int)xh[16 + u * 3 + i3]);
      const f16x2* wp = reinterpret_cast<const f16x2*>(W2H + (384 + u * 8 + w) * 16);
#pragma unroll
      for (int i = 0; i < 8; ++i) acc[i] += xv * wp[i];
    }
  } else if (mm < 96) {
    int tt = mm - 48, w = tt / 3, i3 = tt - w * 3;
#pragma unroll 1
    for (int u = 0; u < 8; ++u) {
      f16x2 xv = as_f16x2((int)xh[16 + u * 3 + i3]);
      const f16x2* wp = reinterpret_cast<const f16x2*>(W2H + (448 + u * 16 + w) * 16);
#pragma unroll
      for (int i = 0; i < 8; ++i) acc[i] += xv * wp[i];
    }
  } else {
    int tt = mm - 96, w = tt / 3, i3 = tt - w * 3;
#pragma unroll 1
    for (int u = 0; u < 8; ++u) {
      f16x2 xv = as_f16x2((int)xh[16 + u * 3 + i3]);
      const f16x2* wp = reinterpret_cast<const f16x2*>(W2H + (576 + u * 8 + w) * 16);
#pragma unroll
      for (int i = 0; i < 8; ++i) acc[i] += xv * wp[i];
    }
  }
#pragma unroll
  for (int i = 0; i < 8; ++i) outw[i] = f16x2_bits(acc[i]);
}

// generate one net's f16 tables for nsrc srcs into LDS (packed-f16 math)
__device__ __forceinline__ void gen_tables(const u16t* __restrict__ W2H,
                                           const unsigned* __restrict__ xh,
                                           u16t* __restrict__ tl,
                                           int nsrc, int tid) {
  for (int idx = tid; idx < nsrc * 120; idx += TPBF) {
    int m, s;
    if (nsrc == SRCS_PER_GRP) {
      m = idx >> 3;
      s = idx & 7;
    } else {
      m = idx / nsrc;
      s = idx - m * nsrc;
    }
    unsigned r[8];
    gen_entry_h(W2H, xh + s * 40, m, r);
    int4* dp = reinterpret_cast<int4*>(&tl[s * SRC_STRIDE_U16 + m * 16]);
    dp[0] = make_int4((int)r[0], (int)r[1], (int)r[2], (int)r[3]);
    dp[1] = make_int4((int)r[4], (int)r[5], (int)r[6], (int)r[7]);
  }
}

// ---------- prep device body ----------

__device__ __forceinline__ void prep_body(int i,
    const float* __restrict__ wk2, const float* __restrict__ wv2,
    const float* __restrict__ wq0, const float* __restrict__ wq1,
    const float* __restrict__ ws0, const float* __restrict__ ws1,
    float* __restrict__ W2Tk, float* __restrict__ W2Tv,
    u16t* __restrict__ W2Hk, u16t* __restrict__ W2Hv,
    float* __restrict__ C0, float* __restrict__ C1) {
  if (i < 10240) {
    int o = i >> 4, j = i & 15;
    float v = wk2[j * 640 + o] * 0.25f;
    W2Tk[i] = v;
    union { _Float16 h; u16t u; } c; c.h = (_Float16)v;
    W2Hk[i] = c.u;
  } else if (i < 20480) {
    int k = i - 10240;
    int o = k >> 4, j = k & 15;
    float v = wv2[j * 640 + o] * 0.25f;
    W2Tv[k] = v;
    union { _Float16 h; u16t u; } c; c.h = (_Float16)v;
    W2Hv[k] = c.u;
  } else if (i < 20736) {
    int k = i - 20480;
    int t = k >> 4, v = k & 15;
    float a = 0.f;
#pragma unroll
    for (int u = 0; u < 16; ++u) a = fmaf(wq0[t * 16 + u] * 0.25f, ws0[u * 16 + v], a);
    C0[k] = a;
  } else if (i < 20800) {
    int k = i - 20736;
    int t = k >> 3, v = k & 7;
    float a = 0.f;
#pragma unroll
    for (int u = 0; u < 8; ++u) a = fmaf(wq1[t * 8 + u] * INV_SQRT8_F, ws1[u * 8 + v], a);
    C1[k] = a;
  }
}

__global__ void k_prep(const float* __restrict__ wk2, const float* __restrict__ wv2,
                       const float* __restrict__ wq0, const float* __restrict__ wq1,
                       const float* __restrict__ ws0, const float* __restrict__ ws1,
                       float* __restrict__ W2Tk, float* __restrict__ W2Tv,
                       u16t* __restrict__ W2Hk, u16t* __restrict__ W2Hv,
                       float* __restrict__ C0, float* __restrict__ C1) {
  int i = blockIdx.x * blockDim.x + threadIdx.x;
  prep_body(i, wk2, wv2, wq0, wq1, ws0, ws1, W2Tk, W2Tv, W2Hk, W2Hv, C0, C1);
}

// fused: hist (blocks < histBlocks) + prep (remaining blocks)
__global__ void k_hist_prep(const int* __restrict__ esrc, const int* __restrict__ edst,
                            int* __restrict__ cnt_s, int* __restrict__ cnt_d, int E,
                            int histBlocks,
                            const float* __restrict__ wk2, const float* __restrict__ wv2,
                            const float* __restrict__ wq0, const float* __restrict__ wq1,
                            const float* __restrict__ ws0, const float* __restrict__ ws1,
                            float* __restrict__ W2Tk, float* __restrict__ W2Tv,
                            u16t* __restrict__ W2Hk, u16t* __restrict__ W2Hv,
                            float* __restrict__ C0, float* __restrict__ C1) {
  if ((int)blockIdx.x < histBlocks) {
    int e = blockIdx.x * blockDim.x + threadIdx.x;
    if (e < E) {
      atomicAdd(&cnt_s[esrc[e]], 1);
      atomicAdd(&cnt_d[edst[e]], 1);
    }
  } else {
    int i = (blockIdx.x - histBlocks) * blockDim.x + threadIdx.x;
    prep_body(i, wk2, wv2, wq0, wq1, ws0, ws1, W2Tk, W2Tv, W2Hk, W2Hv, C0, C1);
  }
}

// node projection device body
__device__ __forceinline__ void node_body(int n, const float* __restrict__ x,
                                          const float* __restrict__ C0,
                                          const float* __restrict__ C1,
                                          float* __restrict__ qs0g,
                                          float* __restrict__ qs1g) {
  float xr[40];
  const float4* p = reinterpret_cast<const float4*>(x + (size_t)n * 40);
#pragma unroll
  for (int q = 0; q < 10; ++q) {
    float4 v = p[q];
    xr[q * 4 + 0] = v.x; xr[q * 4 + 1] = v.y; xr[q * 4 + 2] = v.z; xr[q * 4 + 3] = v.w;
  }
  float o0[16];
#pragma unroll
  for (int v = 0; v < 16; ++v) o0[v] = 0.f;
#pragma unroll
  for (int t = 0; t < 16; ++t) {
    float xt = xr[t];
    const float* c = C0 + t * 16;
#pragma unroll
    for (int v = 0; v < 16; ++v) o0[v] = fmaf(xt, c[v], o0[v]);
  }
  float4* q0p = reinterpret_cast<float4*>(qs0g + (size_t)n * 16);
#pragma unroll
  for (int q = 0; q < 4; ++q)
    q0p[q] = make_float4(o0[q * 4], o0[q * 4 + 1], o0[q * 4 + 2], o0[q * 4 + 3]);

  float o1[24];
#pragma unroll
  for (int v = 0; v < 24; ++v) o1[v] = 0.f;
#pragma unroll
  for (int u = 0; u < 8; ++u) {
    const float* c = C1 + u * 8;
    float xa = xr[16 + u * 3 + 0], xb = xr[16 + u * 3 + 1], xc = xr[16 + u * 3 + 2];
#pragma unroll
    for (int v = 0; v < 8; ++v) {
      float cv = c[v];
      o1[v * 3 + 0] = fmaf(xa, cv, o1[v * 3 + 0]);
      o1[v * 3 + 1] = fmaf(xb, cv, o1[v * 3 + 1]);
      o1[v * 3 + 2] = fmaf(xc, cv, o1[v * 3 + 2]);
    }
  }
  float4* q1p = reinterpret_cast<float4*>(qs1g + (size_t)n * 24);
#pragma unroll
  for (int q = 0; q < 6; ++q)
    q1p[q] = make_float4(o1[q * 4], o1[q * 4 + 1], o1[q * 4 + 2], o1[q * 4 + 3]);
}

__global__ void k_node(const float* __restrict__ x, const float* __restrict__ C0,
                       const float* __restrict__ C1, float* __restrict__ qs0g,
                       float* __restrict__ qs1g, int N) {
  int n = blockIdx.x * blockDim.x + threadIdx.x;
  if (n < N) node_body(n, x, C0, C1, qs0g, qs1g);
}

// ---------- CSR build ----------

__global__ void k_hist1(const int* __restrict__ key, int* __restrict__ cnt, int E) {
  int e = blockIdx.x * blockDim.x + threadIdx.x;
  if (e < E) atomicAdd(&cnt[key[e]], 1);
}

// fused: scan (blocks 0,1) + node projection (blocks 2+)
__global__ __launch_bounds__(1024) void k_scan_node(
    const int* __restrict__ cnt_s, int* __restrict__ off_s, int* __restrict__ cur_s,
    const int* __restrict__ cnt_d, int* __restrict__ off_d, int* __restrict__ cur_d,
    int N,
    const float* __restrict__ x, const float* __restrict__ C0,
    const float* __restrict__ C1, float* __restrict__ qs0g,
    float* __restrict__ qs1g) {
  __shared__ int ls[1024];
  if (blockIdx.x < 2) {
    const int* __restrict__ cnt = blockIdx.x ? cnt_d : cnt_s;
    int* __restrict__ off = blockIdx.x ? off_d : off_s;
    int* __restrict__ cur = blockIdx.x ? cur_d : cur_s;
    int tid = threadIdx.x;
    int per = (N + 1023) >> 10;
    int base = tid * per;
    int sum = 0;
    for (int j = 0; j < per; ++j) {
      int idx = base + j;
      if (idx < N) sum += cnt[idx];
    }
    ls[tid] = sum;
    __syncthreads();
    for (int d = 1; d < 1024; d <<= 1) {
      int v = (tid >= d) ? ls[tid - d] : 0;
      __syncthreads();
      ls[tid] += v;
      __syncthreads();
    }
    int run = ls[tid] - sum;
    for (int j = 0; j < per; ++j) {
      int idx = base + j;
      if (idx < N) {
        off[idx] = run;
        cur[idx] = run;
        run += cnt[idx];
      }
    }
    if (tid == 1023) off[N] = run;
  } else {
    int n = (blockIdx.x - 2) * 1024 + threadIdx.x;
    if (n < N) node_body(n, x, C0, C1, qs0g, qs1g);
  }
}

// general scan (fallback path)
__global__ __launch_bounds__(1024) void k_scan2(const int* __restrict__ cnt_s,
                                                int* __restrict__ off_s,
                                                int* __restrict__ cur_s,
                                                const int* __restrict__ cnt_d,
                                                int* __restrict__ off_d,
                                                int* __restrict__ cur_d, int N) {
  const int* __restrict__ cnt = blockIdx.x ? cnt_d : cnt_s;
  int* __restrict__ off = blockIdx.x ? off_d : off_s;
  int* __restrict__ cur = blockIdx.x ? cur_d : cur_s;
  __shared__ int ls[1024];
  int tid = threadIdx.x;
  int per = (N + 1023) >> 10;
  int base = tid * per;
  int sum = 0;
  for (int j = 0; j < per; ++j) {
    int idx = base + j;
    if (idx < N) sum += cnt[idx];
  }
  ls[tid] = sum;
  __syncthreads();
  for (int d = 1; d < 1024; d <<= 1) {
    int v = (tid >= d) ? ls[tid - d] : 0;
    __syncthreads();
    ls[tid] += v;
    __syncthreads();
  }
  int run = ls[tid] - sum;
  for (int j = 0; j < per; ++j) {
    int idx = base + j;
    if (idx < N) {
      off[idx] = run;
      cur[idx] = run;
      run += cnt[idx];
    }
  }
  if (tid == 1023) off[N] = run;
}

// place: write sorted (src,dst) edge arrays + dst-order position list
__global__ void k_place3(const int* __restrict__ esrc, const int* __restrict__ edst,
                         int* __restrict__ cur_s, int* __restrict__ cur_d,
                         int* __restrict__ es2, int* __restrict__ ed2,
                         int* __restrict__ idx, int E) {
  int e = blockIdx.x * blockDim.x + threadIdx.x;
  if (e < E) {
    int s = esrc[e], d = edst[e];
    int p = atomicAdd(&cur_s[s], 1);
    es2[p] = s;
    ed2[p] = d;
    int q = atomicAdd(&cur_d[d], 1);
    idx[q] = p;
  }
}

__global__ void k_place(const int* __restrict__ key, int* __restrict__ cursor,
                        int* __restrict__ perm, int E) {
  int e = blockIdx.x * blockDim.x + threadIdx.x;
  if (e < E) {
    int p = atomicAdd(&cursor[key[e]], 1);
    perm[p] = e;
  }
}

// ---------- fused table-gen + edge kernel (f16 tables + fdot2, chunked) ----------

__global__ __launch_bounds__(TPBF) void k_fused(
    const float* __restrict__ x, const float* __restrict__ pos,
    const int* __restrict__ es2, const int* __restrict__ ed2,
    const int* __restrict__ off_s,
    const float* __restrict__ W1k, const u16t* __restrict__ W2Hk,
    const float* __restrict__ W1v, const u16t* __restrict__ W2Hv,
    const float* __restrict__ qs0g, const float* __restrict__ qs1g,
    float* __restrict__ s_out, u16t* __restrict__ stg, int N) {
  __shared__ __align__(16) u16t tl[SRCS_PER_GRP * SRC_STRIDE_U16];
  __shared__ unsigned xh[SRCS_PER_GRP * 40];   // f16x2 splats of x rows
  int tid = threadIdx.x;
  int base = blockIdx.x * SRCS_PER_GRP;
  int nsrc = min(SRCS_PER_GRP, N - base);
  int glo = off_s[base], ghi = off_s[base + nsrc];

  // stage x rows as f16 splats
  for (int idx = tid; idx < nsrc * 40; idx += TPBF) {
    int s = idx / 40, u = idx - s * 40;
    float v = x[(size_t)(base + s) * 40 + u];
    f16x2 hh; hh.x = (_Float16)v; hh.y = hh.x;
    xh[s * 40 + u] = f16x2_bits(hh);
  }
  __syncthreads();

  // KEY tables
  gen_tables(W2Hk, xh, tl, nsrc, tid);
  __syncthreads();

  for (int p0 = glo; p0 < ghi; p0 += TPBF) {
    int p = p0 + tid;
    bool act = p < ghi;

    // per-edge state carried across the LDS table swap (registers)
    float shx = 0.f, shy = 0.f, shz = 0.f;
    int sloc = 0;
    f16x2 hvp[8];
#pragma unroll
    for (int j = 0; j < 8; ++j) { hvp[j].x = (_Float16)0.f; hvp[j].y = (_Float16)0.f; }

    if (act) {
      int src = es2[p];
      int dst = ed2[p];
      sloc = src - base;
      float hk[16], hv[16];
      compute_h2s(pos, W1k, W1v, src, dst, shx, shy, shz, hk, hv);
      f16x2 hkp[8];
      pack_h16(hk, hkp);
      pack_h16(hv, hvp);

      const u16t* tk = &tl[sloc * SRC_STRIDE_U16];
      // ---- key: similarity ----
      const float4* q0p = reinterpret_cast<const float4*>(qs0g + (size_t)dst * 16);
      float S0 = 0.f;
#pragma unroll 2
      for (int w4 = 0; w4 < 4; ++w4) {
        float4 qq = q0p[w4];
        float q[4] = {qq.x, qq.y, qq.z, qq.w};
#pragma unroll
        for (int k = 0; k < 4; ++k) {
          float t0 = dotjh(tk + (w4 * 4 + k) * 16, hkp);
          float t3x = dotjh(tk + (48 + w4 * 12 + k * 3 + 0) * 16, hkp);
          float t3y = dotjh(tk + (48 + w4 * 12 + k * 3 + 1) * 16, hkp);
          float t3z = dotjh(tk + (48 + w4 * 12 + k * 3 + 2) * 16, hkp);
          S0 = fmaf(q[k], fmaf(INV3_F, t3x * shx + t3y * shy + t3z * shz, t0), S0);
        }
      }
      const float4* q1p = reinterpret_cast<const float4*>(qs1g + (size_t)dst * 24);
      float S1 = 0.f;
#pragma unroll 2
      for (int w4 = 0; w4 < 2; ++w4) {
        float4 qa = q1p[w4 * 3 + 0];
        float4 qb = q1p[w4 * 3 + 1];
        float4 qc = q1p[w4 * 3 + 2];
        float q[12] = {qa.x, qa.y, qa.z, qa.w, qb.x, qb.y, qb.z, qb.w,
                       qc.x, qc.y, qc.z, qc.w};
#pragma unroll
        for (int k = 0; k < 4; ++k) {
          float qx = q[k * 3 + 0], qy = q[k * 3 + 1], qz = q[k * 3 + 2];
          float t1 = dotjh(tk + (16 + w4 * 4 + k) * 16, hkp);
          float t2x = dotjh(tk + (24 + w4 * 12 + k * 3 + 0) * 16, hkp);
          float t2y = dotjh(tk + (24 + w4 * 12 + k * 3 + 1) * 16, hkp);
          float t2z = dotjh(tk + (24 + w4 * 12 + k * 3 + 2) * 16, hkp);
          float c0 = dotjh(tk + (96 + w4 * 12 + k * 3 + 0) * 16, hkp);
          float c1 = dotjh(tk + (96 + w4 * 12 + k * 3 + 1) * 16, hkp);
          float c2 = dotjh(tk + (96 + w4 * 12 + k * 3 + 2) * 16, hkp);
          float crx = c1 * shz - c2 * shy;
          float cry = c2 * shx - c0 * shz;
          float crz = c0 * shy - c1 * shx;
          float qdots = qx * shx + qy * shy + qz * shz;
          S1 += INV3_F * (t1 * qdots + t2x * qx + t2y * qy + t2z * qz) +
                INV6_F * (crx * qx + cry * qy + crz * qz);
        }
      }
      s_out[p] = PWSIM_F * (PW0_F * S0 + PW1_F * INV3_F * S1);
    }
    __syncthreads();

    // VALUE tables (overwrite LDS)
    gen_tables(W2Hv, xh, tl, nsrc, tid);
    __syncthreads();

    if (act) {
      const u16t* tv = &tl[sloc * SRC_STRIDE_U16];
      u16t* sp = stg + (size_t)p * 40;
#pragma unroll 2
      for (int w4 = 0; w4 < 4; ++w4) {
        float f[4];
#pragma unroll
        for (int k = 0; k < 4; ++k) {
          float t0 = dotjh(tv + (w4 * 4 + k) * 16, hvp);
          float t3x = dotjh(tv + (48 + w4 * 12 + k * 3 + 0) * 16, hvp);
          float t3y = dotjh(tv + (48 + w4 * 12 + k * 3 + 1) * 16, hvp);
          float t3z = dotjh(tv + (48 + w4 * 12 + k * 3 + 2) * 16, hvp);
          f[k] = PW0_F * fmaf(INV3_F, t3x * shx + t3y * shy + t3z * shz, t0);
        }
        f16x2 pa; pa.x = (_Float16)f[0]; pa.y = (_Float16)f[1];
        f16x2 pb; pb.x = (_Float16)f[2]; pb.y = (_Float16)f[3];
        int2 pk;
        pk.x = (int)f16x2_bits(pa);
        pk.y = (int)f16x2_bits(pb);
        *reinterpret_cast<int2*>(sp + w4 * 4) = pk;
      }
#pragma unroll 2
      for (int w4 = 0; w4 < 2; ++w4) {
        float f[12];
#pragma unroll
        for (int k = 0; k < 4; ++k) {
          float t1 = dotjh(tv + (16 + w4 * 4 + k) * 16, hvp);
          float t2x = dotjh(tv + (24 + w4 * 12 + k * 3 + 0) * 16, hvp);
          float t2y = dotjh(tv + (24 + w4 * 12 + k * 3 + 1) * 16, hvp);
          float t2z = dotjh(tv + (24 + w4 * 12 + k * 3 + 2) * 16, hvp);
          float c0 = dotjh(tv + (96 + w4 * 12 + k * 3 + 0) * 16, hvp);
          float c1 = dotjh(tv + (96 + w4 * 12 + k * 3 + 1) * 16, hvp);
          float c2 = dotjh(tv + (96 + w4 * 12 + k * 3 + 2) * 16, hvp);
          float crx = c1 * shz - c2 * shy;
          float cry = c2 * shx - c0 * shz;
          float crz = c0 * shy - c1 * shx;
          f[k * 3 + 0] = PW1_F * (INV3_F * fmaf(t1, shx, t2x) + INV6_F * crx);
          f[k * 3 + 1] = PW1_F * (INV3_F * fmaf(t1, shy, t2y) + INV6_F * cry);
          f[k * 3 + 2] = PW1_F * (INV3_F * fmaf(t1, shz, t2z) + INV6_F * crz);
        }
#pragma unroll
        for (int g = 0; g < 3; ++g) {
          f16x2 pa; pa.x = (_Float16)f[g * 4 + 0]; pa.y = (_Float16)f[g * 4 + 1];
          f16x2 pb; pb.x = (_Float16)f[g * 4 + 2]; pb.y = (_Float16)f[g * 4 + 3];
          int2 pk;
          pk.x = (int)f16x2_bits(pa);
          pk.y = (int)f16x2_bits(pb);
          *reinterpret_cast<int2*>(sp + 16 + w4 * 12 + g * 4) = pk;
        }
      }
    }

    if (p0 + TPBF < ghi) {   // more chunks: restore KEY tables
      __syncthreads();
      gen_tables(W2Hk, xh, tl, nsrc, tid);
      __syncthreads();
    }
  }
}

// ---------- fused per-node softmax + gather (shuffle-shared coef) ----------

__global__ void k_smg(const float* __restrict__ s, const u16t* __restrict__ stg,
                      const int* __restrict__ off, const int* __restrict__ idx,
                      float* __restrict__ out, int N) {
  int gid = blockIdx.x * blockDim.x + threadIdx.x;
  int wid = gid >> 6;
  int lane = threadIdx.x & 63;
  if (wid >= N) return;
  int lo = off[wid], hi = off[wid + 1];
  float m = -1e30f;
  for (int q = lo + lane; q < hi; q += 64) m = fmaxf(m, s[idx[q]]);
#pragma unroll
  for (int d = 32; d; d >>= 1) m = fmaxf(m, __shfl_xor(m, d));
  float sum = 0.f;
  for (int q = lo + lane; q < hi; q += 64) sum += __expf(s[idx[q]] - m);
#pragma unroll
  for (int d = 32; d; d >>= 1) sum += __shfl_xor(sum, d);
  float inv = 1.0f / sum;
  float acc = 0.f;
  for (int q0 = lo; q0 < hi; q0 += 64) {
    int q = q0 + lane;
    int pv = 0;
    float cv = 0.f;
    if (q < hi) {
      pv = idx[q];
      cv = sqrtf(__expf(s[pv] - m) * inv);
    }
    int nj = min(64, hi - q0);
    for (int j = 0; j < nj; ++j) {
      float cj = __shfl(cv, j);
      int pj = __shfl(pv, j);
      if (lane < 40)
        acc = fmaf(cj, f16b2f(stg[(size_t)pj * 40 + lane]), acc);
    }
  }
  if (lane < 40) out[(size_t)wid * 40 + lane] = acc;
}

// ---------- fallback (round-2) fused edge kernel, fp32 staging ----------

__global__ __launch_bounds__(TPB) void k_edge_fused(
    const float* __restrict__ x, const float* __restrict__ pos,
    const int* __restrict__ esrc, const int* __restrict__ edst,
    const int* __restrict__ perm,
    const float* __restrict__ W1k, const float* __restrict__ W2Tk,
    const float* __restrict__ W1v, const float* __restrict__ W2Tv,
    const float* __restrict__ qs0g, const float* __restrict__ qs1g,
    float* __restrict__ s_out, float* __restrict__ staging, int E) {
  __shared__ float xs[TPB * 41];
  int p = blockIdx.x * TPB + threadIdx.x;
  if (p >= E) return;
  int e = perm[p];
  int src = esrc[e], dst = edst[e];

  float* myx = &xs[threadIdx.x * 41];
  const float4* xrow = reinterpret_cast<const float4*>(x + (size_t)src * 40);
#pragma unroll
  for (int q = 0; q < 10; ++q) {
    float4 v = xrow[q];
    myx[q * 4 + 0] = v.x; myx[q * 4 + 1] = v.y; myx[q * 4 + 2] = v.z; myx[q * 4 + 3] = v.w;
  }

  float sh1[3], hk[16], hv[16];
  compute_h2s(pos, W1k, W1v, src, dst, sh1[0], sh1[1], sh1[2], hk, hv);

  {
    float qs0[16];
    {
      const float4* qp = reinterpret_cast<const float4*>(qs0g + (size_t)dst * 16);
#pragma unroll
      for (int q = 0; q < 4; ++q) {
        float4 v = qp[q];
        qs0[q * 4 + 0] = v.x; qs0[q * 4 + 1] = v.y; qs0[q * 4 + 2] = v.z; qs0[q * 4 + 3] = v.w;
      }
    }
    float qs1[24];
    {
      const float4* qp = reinterpret_cast<const float4*>(qs1g + (size_t)dst * 24);
#pragma unroll
      for (int q = 0; q < 6; ++q) {
        float4 v = qp[q];
        qs1[q * 4 + 0] = v.x; qs1[q * 4 + 1] = v.y; qs1[q * 4 + 2] = v.z; qs1[q * 4 + 3] = v.w;
      }
    }
    float qsh[8];
#pragma unroll
    for (int w = 0; w < 8; ++w)
      qsh[w] = qs1[w * 3] * sh1[0] + qs1[w * 3 + 1] * sh1[1] + qs1[w * 3 + 2] * sh1[2];

    float S0a = 0.f, S0b = 0.f, S1a = 0.f, S1b = 0.f, S1c = 0.f;
#pragma unroll 1
    for (int u = 0; u < 16; ++u) {
      const float* base = W2Tk + (u * 16) * 16;
      float accu = 0.f;
#pragma unroll
      for (int w = 0; w < 16; ++w) accu = fmaf(dot16u(base + w * 16, hk), qs0[w], accu);
      S0a = fmaf(accu, myx[u], S0a);
    }
#pragma unroll 1
    for (int u = 0; u < 16; ++u) {
      const float* base = W2Tk + (256 + u * 8) * 16;
      float accu = 0.f;
#pragma unroll
      for (int w = 0; w < 8; ++w) accu = fmaf(dot16u(base + w * 16, hk), qsh[w], accu);
      S1a = fmaf(accu, myx[u], S1a);
    }
#pragma unroll 1
    for (int u = 0; u < 8; ++u) {
      const float* base = W2Tk + (384 + u * 8) * 16;
      float x1a = myx[16 + u * 3 + 0], x1b = myx[16 + u * 3 + 1], x1c = myx[16 + u * 3 + 2];
      float accu = 0.f;
#pragma unroll
      for (int w = 0; w < 8; ++w) {
        float t = qs1[w * 3] * x1a + qs1[w * 3 + 1] * x1b + qs1[w * 3 + 2] * x1c;
        accu = fmaf(dot16u(base + w * 16, hk), t, accu);
      }
      S1b += accu;
    }
#pragma unroll 1
    for (int u = 0; u < 8; ++u) {
      const float* base = W2Tk + (448 + u * 16) * 16;
      float x1a = myx[16 + u * 3 + 0], x1b = myx[16 + u * 3 + 1], x1c = myx[16 + u * 3 + 2];
      float du = x1a * sh1[0] + x1b * sh1[1] + x1c * sh1[2];
      float accu = 0.f;
#pragma unroll
      for (int w = 0; w < 16; ++w) accu = fmaf(dot16u(base + w * 16, hk), qs0[w], accu);
      S0b = fmaf(accu, du, S0b);
    }
#pragma unroll 1
    for (int u = 0; u < 8; ++u) {
      const float* base = W2Tk + (576 + u * 8) * 16;
      float x1a = myx[16 + u * 3 + 0], x1b = myx[16 + u * 3 + 1], x1c = myx[16 + u * 3 + 2];
      float cx = x1b * sh1[2] - x1c * sh1[1];
      float cy = x1c * sh1[0] - x1a * sh1[2];
      float cz = x1a * sh1[1] - x1b * sh1[0];
      float accu = 0.f;
#pragma unroll
      for (int w = 0; w < 8; ++w) {
        float t = qs1[w * 3] * cx + qs1[w * 3 + 1] * cy + qs1[w * 3 + 2] * cz;
        accu = fmaf(dot16u(base + w * 16, hk), t, accu);
      }
      S1c += accu;
    }
    s_out[p] = PWSIM_F * (PW0_F * (S0a + INV3_F * S0b) +
                          (INV3_F * PW1_F) * (INV3_F * S1a + INV3_F * S1b + INV6_F * S1c));
  }

  float v0[16];
#pragma unroll
  for (int w = 0; w < 16; ++w) v0[w] = 0.f;
  float v1[24];
#pragma unroll
  for (int w = 0; w < 24; ++w) v1[w] = 0.f;

#pragma unroll 1
  for (int u = 0; u < 16; ++u) {
    const float* base = W2Tv + (u * 16) * 16;
    float xu = myx[u];
#pragma unroll
    for (int w = 0; w < 16; ++w) v0[w] = fmaf(dot16u(base + w * 16, hv), xu, v0[w]);
  }
  {
    float aw[8];
#pragma unroll
    for (int w = 0; w < 8; ++w) aw[w] = 0.f;
#pragma unroll 1
    for (int u = 0; u < 16; ++u) {
      const float* base = W2Tv + (256 + u * 8) * 16;
      float xu = myx[u];
#pragma unroll
      for (int w = 0; w < 8; ++w) aw[w] = fmaf(dot16u(base + w * 16, hv), xu, aw[w]);
    }
#pragma unroll
    for (int w = 0; w < 8; ++w) {
      float t = INV3_F * aw[w];
      v1[w * 3 + 0] = fmaf(t, sh1[0], v1[w * 3 + 0]);
      v1[w * 3 + 1] = fmaf(t, sh1[1], v1[w * 3 + 1]);
      v1[w * 3 + 2] = fmaf(t, sh1[2], v1[w * 3 + 2]);
    }
  }
#pragma unroll 1
  for (int u = 0; u < 8; ++u) {
    const float* base = W2Tv + (384 + u * 8) * 16;
    float a0 = INV3_F * myx[16 + u * 3 + 0];
    float a1 = INV3_F * myx[16 + u * 3 + 1];
    float a2 = INV3_F * myx[16 + u * 3 + 2];
#pragma unroll
    for (int w = 0; w < 8; ++w) {
      float wk = dot16u(base + w * 16, hv);
      v1[w * 3 + 0] = fmaf(wk, a0, v1[w * 3 + 0]);
      v1[w * 3 + 1] = fmaf(wk, a1, v1[w * 3 + 1]);
      v1[w * 3 + 2] = fmaf(wk, a2, v1[w * 3 + 2]);
    }
  }
#pragma unroll 1
  for (int u = 0; u < 8; ++u) {
    const float* base = W2Tv + (448 + u * 16) * 16;
    float x1a = myx[16 + u * 3 + 0], x1b = myx[16 + u * 3 + 1], x1c = myx[16 + u * 3 + 2];
    float du = INV3_F * (x1a * sh1[0] + x1b * sh1[1] + x1c * sh1[2]);
#pragma unroll
    for (int w = 0; w < 16; ++w) v0[w] = fmaf(dot16u(base + w * 16, hv), du, v0[w]);
  }
#pragma unroll 1
  for (int u = 0; u < 8; ++u) {
    const float* base = W2Tv + (576 + u * 8) * 16;
    float x1a = myx[16 + u * 3 + 0], x1b = myx[16 + u * 3 + 1], x1c = myx[16 + u * 3 + 2];
    float cx = INV6_F * (x1b * sh1[2] - x1c * sh1[1]);
    float cy = INV6_F * (x1c * sh1[0] - x1a * sh1[2]);
    float cz = INV6_F * (x1a * sh1[1] - x1b * sh1[0]);
#pragma unroll
    for (int w = 0; w < 8; ++w) {
      float wk = dot16u(base + w * 16, hv);
      v1[w * 3 + 0] = fmaf(wk, cx, v1[w * 3 + 0]);
      v1[w * 3 + 1] = fmaf(wk, cy, v1[w * 3 + 1]);
      v1[w * 3 + 2] = fmaf(wk, cz, v1[w * 3 + 2]);
    }
  }

  float outv[40];
#pragma unroll
  for (int w = 0; w < 16; ++w) outv[w] = PW0_F * v0[w];
#pragma unroll
  for (int w = 0; w < 24; ++w) outv[16 + w] = PW1_F * v1[w];
  float4* st = reinterpret_cast<float4*>(staging + (size_t)p * 40);
#pragma unroll
  for (int q = 0; q < 10; ++q)
    st[q] = make_float4(outv[q * 4], outv[q * 4 + 1], outv[q * 4 + 2], outv[q * 4 + 3]);
}

__global__ void k_softmax(const float* __restrict__ s, const int* __restrict__ off,
                          float* __restrict__ coef, int N) {
  int gid = blockIdx.x * blockDim.x + threadIdx.x;
  int wid = gid >> 6;
  int lane = threadIdx.x & 63;
  if (wid >= N) return;
  int lo = off[wid], hi = off[wid + 1];
  float m = -1e30f;
  for (int p = lo + lane; p < hi; p += 64) m = fmaxf(m, s[p]);
#pragma unroll
  for (int d = 32; d; d >>= 1) m = fmaxf(m, __shfl_xor(m, d));
  float sum = 0.f;
  for (int p = lo + lane; p < hi; p += 64) sum += __expf(s[p] - m);
#pragma unroll
  for (int d = 32; d; d >>= 1) sum += __shfl_xor(sum, d);
  float inv = 1.0f / sum;
  for (int p = lo + lane; p < hi; p += 64)
    coef[p] = sqrtf(__expf(s[p] - m) * inv);
}

__global__ void k_gather(const float* __restrict__ staging, const float* __restrict__ coef,
                         const int* __restrict__ off, float* __restrict__ out, int N) {
  int gid = blockIdx.x * blockDim.x + threadIdx.x;
  int wid = gid >> 6;
  int lane = threadIdx.x & 63;
  if (wid >= N) return;
  int lo = off[wid], hi = off[wid + 1];
  if (lane < 40) {
    float acc = 0.f;
    for (int p = lo; p < hi; ++p)
      acc = fmaf(coef[p], staging[(size_t)p * 40 + lane], acc);
    out[(size_t)wid * 40 + lane] = acc;
  }
}

// ---------- host launcher ----------

extern "C" void kernel_launch(void* const* d_in, const int* in_sizes, int n_in,
                              void* d_out, int out_size, void* d_ws, size_t ws_size,
                              hipStream_t stream) {
  const float* x   = (const float*)d_in[0];
  const float* pos = (const float*)d_in[1];
  const int* esrc  = (const int*)d_in[2];
  const int* edst  = (const int*)d_in[3];
  const float* wk1 = (const float*)d_in[4];
  const float* wk2 = (const float*)d_in[5];
  const float* wv1 = (const float*)d_in[6];
  const float* wv2 = (const float*)d_in[7];
  const float* wq0 = (const float*)d_in[8];
  const float* wq1 = (const float*)d_in[9];
  const float* ws0 = (const float*)d_in[10];
  const float* ws1 = (const float*)d_in[11];

  int E = in_sizes[2];
  int N = in_sizes[0] / 40;

  float* ws = (float*)d_ws;
  float* W2Tk = ws;                        // 10240 f32
  float* W2Tv = ws + 10240;                // 10240 f32
  float* C0   = ws + 20480;                // 256
  float* C1   = ws + 20736;                // 64
  u16t* W2Hk  = (u16t*)(ws + 20800);       // 10240 u16
  u16t* W2Hv  = W2Hk + 10240;              // 10240 u16
  float* qs0g = ws + 20800 + 10240;        // N*16  (20480 u16 = 10240 f32)
  float* qs1g = qs0g + (size_t)N * 16;     // N*24
  float* base2 = qs1g + (size_t)N * 24;

  // fast-path layout
  float* s_ws = base2;                                  // E
  int* cnt_s  = (int*)(s_ws + (size_t)E);               // N
  int* cnt_d  = cnt_s + N;                              // N
  int* off_s  = cnt_d + N;                              // N+1
  int* cur_s  = off_s + N + 1;                          // N
  int* off_d  = cur_s + N;                              // N+1
  int* cur_d  = off_d + N + 1;                          // N
  int* es2    = cur_d + N;                              // E
  int* ed2    = es2 + (size_t)E;                        // E
  int* idxd   = ed2 + (size_t)E;                        // E
  u16t* stgb  = (u16t*)(idxd + (size_t)E);              // E*40 u16
  size_t need_fast = (size_t)((char*)(stgb + (size_t)E * 40) - (char*)d_ws);

  if (ws_size >= need_fast) {
    hipMemsetAsync(cnt_s, 0, sizeof(int) * (size_t)(2 * N), stream);
    int histBlocks = (E + 255) / 256;
    int prepBlocks = (20800 + 255) / 256;
    k_hist_prep<<<histBlocks + prepBlocks, 256, 0, stream>>>(
        esrc, edst, cnt_s, cnt_d, E, histBlocks,
        wk2, wv2, wq0, wq1, ws0, ws1, W2Tk, W2Tv, W2Hk, W2Hv, C0, C1);
    int nodeBlocks = (N + 1023) / 1024;
    k_scan_node<<<2 + nodeBlocks, 1024, 0, stream>>>(
        cnt_s, off_s, cur_s, cnt_d, off_d, cur_d, N, x, C0, C1, qs0g, qs1g);
    k_place3<<<(E + 255) / 256, 256, 0, stream>>>(esrc, edst, cur_s, cur_d,
                                                  es2, ed2, idxd, E);
    int ng = (N + SRCS_PER_GRP - 1) / SRCS_PER_GRP;
    k_fused<<<ng, TPBF, 0, stream>>>(x, pos, es2, ed2, off_s,
                                     wk1, W2Hk, wv1, W2Hv, qs0g, qs1g,
                                     s_ws, stgb, N);
    k_smg<<<((N * 64) + 255) / 256, 256, 0, stream>>>(s_ws, stgb, off_d, idxd,
                                                      (float*)d_out, N);
  } else {
    // fallback: round-2 dst-sorted fp32-staging path
    float* coefF = s_ws + (size_t)E;                    // E (reuse area)
    int* cnt    = (int*)(coefF + (size_t)E);            // N
    int* off    = cnt + N;                              // N+1
    int* cursor = off + N + 1;                          // N
    int* permF  = cursor + N;                           // E
    float* staging = (float*)(permF + (size_t)E);       // E*40

    k_prep<<<(20800 + 255) / 256, 256, 0, stream>>>(wk2, wv2, wq0, wq1, ws0, ws1,
                                                    W2Tk, W2Tv, W2Hk, W2Hv, C0, C1);
    k_node<<<(N + 255) / 256, 256, 0, stream>>>(x, C0, C1, qs0g, qs1g, N);
    hipMemsetAsync(cnt, 0, sizeof(int) * (size_t)N, stream);
    k_hist1<<<(E + 255) / 256, 256, 0, stream>>>(edst, cnt, E);
    k_scan2<<<1, 1024, 0, stream>>>(cnt, off, cursor, cnt, off, cursor, N);
    k_place<<<(E + 255) / 256, 256, 0, stream>>>(edst, cursor, permF, E);
    k_edge_fused<<<(E + TPB - 1) / TPB, TPB, 0, stream>>>(
        x, pos, esrc, edst, permF, wk1, W2Tk, wv1, W2Tv, qs0g, qs1g,
        s_ws, staging, E);
    k_softmax<<<((N * 64) + 255) / 256, 256, 0, stream>>>(s_ws, off, coefF, N);
    k_gather<<<((N * 64) + 255) / 256, 256, 0, stream>>>(staging, coefF, off,
                                                         (float*)d_out, N);
  }
}